// Round 5
// baseline (375.057 us; speedup 1.0000x reference)
//
#include <hip/hip_runtime.h>
#include <hip/hip_bf16.h>

#define NPTS  20000
#define DIM   128
#define NA    1024
#define NTASK 2048
#define G     8        // tasks per dist block
#define P     4        // points per thread
#define TILE  1024     // P * 256 points per dist block
#define KSEL  50
#define GAMMA 1.0f
#define WIN   1024     // candidate window above per-task min (u8-metric units)
#define NB    64       // fine bins in window (width 16)
#define CAP   4096

typedef unsigned char  u8t;
typedef unsigned short u16t;

static __device__ __forceinline__ unsigned sad8(unsigned a, unsigned b, unsigned c) {
#if __has_builtin(__builtin_amdgcn_sad_u8)
    return __builtin_amdgcn_sad_u8(a, b, c);
#else
    unsigned d;
    asm("v_sad_u8 %0, %1, %2, %3" : "=v"(d) : "v"(a), "v"(b), "v"(c));
    return d;
#endif
}

__global__ __launch_bounds__(256) void init_kernel(float* out, unsigned* gmin, unsigned* gmax) {
    const int i = (int)blockIdx.x * 256 + (int)threadIdx.x;
    if (i < NTASK) gmin[i] = 0xFFFFFFFFu;
    if (i == 0) { out[0] = 0.0f; gmax[0] = 0u; }
}

__global__ __launch_bounds__(256) void maxabs_kernel(
    const float* __restrict__ o1, const float* __restrict__ o2,
    unsigned* __restrict__ gmax)
{
    const int nt = (int)gridDim.x * 256;
    const float4* a = (const float4*)o1;
    const float4* b = (const float4*)o2;
    float m = 0.0f;
    for (int i = (int)blockIdx.x * 256 + (int)threadIdx.x; i < NPTS * DIM / 4; i += nt) {
        const float4 x = a[i], y = b[i];
        m = fmaxf(m, fmaxf(fmaxf(fabsf(x.x), fabsf(x.y)), fmaxf(fabsf(x.z), fabsf(x.w))));
        m = fmaxf(m, fmaxf(fmaxf(fabsf(y.x), fabsf(y.y)), fmaxf(fabsf(y.z), fabsf(y.w))));
    }
    #pragma unroll
    for (int off = 32; off >= 1; off >>= 1) m = fmaxf(m, __shfl_xor(m, off));
    if ((threadIdx.x & 63) == 0) atomicMax(gmax, __float_as_uint(m));  // m >= 0: bit order == float order
}

__global__ __launch_bounds__(256) void quant_kernel(
    const float* __restrict__ o1, const float* __restrict__ o2,
    u8t* __restrict__ q1, u8t* __restrict__ q2,
    const unsigned* __restrict__ gmax)
{
    const float M = __uint_as_float(*gmax);
    const float s = 255.0f / (2.0f * M);
    const int nt = (int)gridDim.x * 256;
    const float4* a = (const float4*)o1;
    const float4* b = (const float4*)o2;
    unsigned* qa = (unsigned*)q1;
    unsigned* qb = (unsigned*)q2;
    for (int i = (int)blockIdx.x * 256 + (int)threadIdx.x; i < NPTS * DIM / 4; i += nt) {
        const float4 x = a[i];
        unsigned u0 = __float2uint_rn((x.x + M) * s); if (u0 > 255u) u0 = 255u;
        unsigned u1 = __float2uint_rn((x.y + M) * s); if (u1 > 255u) u1 = 255u;
        unsigned u2 = __float2uint_rn((x.z + M) * s); if (u2 > 255u) u2 = 255u;
        unsigned u3 = __float2uint_rn((x.w + M) * s); if (u3 > 255u) u3 = 255u;
        qa[i] = u0 | (u1 << 8) | (u2 << 16) | (u3 << 24);
        const float4 y = b[i];
        unsigned v0 = __float2uint_rn((y.x + M) * s); if (v0 > 255u) v0 = 255u;
        unsigned v1 = __float2uint_rn((y.y + M) * s); if (v1 > 255u) v1 = 255u;
        unsigned v2 = __float2uint_rn((y.z + M) * s); if (v2 > 255u) v2 = 255u;
        unsigned v3 = __float2uint_rn((y.w + M) * s); if (v3 > 255u) v3 = 255u;
        qb[i] = v0 | (v1 << 8) | (v2 << 16) | (v3 << 24);
    }
}

// L1 distances via v_sad_u8 for G tasks x TILE points; writes exact u16
// distances + fused per-task min (register shuffle reduce, 1 atomicMin per
// task per block -- NO LDS histogram, that was round 4's 1.7e7-conflict bug).
__global__ __launch_bounds__(256) void dist_kernel(
    const u8t* __restrict__ q1, const u8t* __restrict__ q2,
    const int* __restrict__ anchor1, const int* __restrict__ anchor2,
    u16t* __restrict__ wsd, unsigned* __restrict__ gmin, int chunk_start)
{
    __shared__ uint4 sa[G][8];            // 8 tasks x 128 u8 = 1 KB
    __shared__ unsigned smin[4][G];

    const int tid = threadIdx.x;
    const int t0 = chunk_start + (int)blockIdx.x * G;

    if (tid < G * 8) {
        const int g = tid >> 3, c = tid & 7;
        const int t = t0 + g;
        int row; const u8t* src;
        if (t < NA) { row = anchor1[t];      src = q1; }
        else        { row = anchor2[t - NA]; src = q2; }
        sa[g][c] = ((const uint4*)(src + (size_t)row * DIM))[c];
    }
    __syncthreads();

    const u8t* baseq = (t0 < NA) ? q2 : q1;
    const int n0 = (int)blockIdx.y * TILE + tid * P;
    const bool valid = (n0 < NPTS);                 // n0 multiple of 4, NPTS%4==0
    const int nc = valid ? n0 : (NPTS - P);
    const uint4* rp = (const uint4*)(baseq + (size_t)nc * DIM);  // 4 rows x 8 uint4

    unsigned acc[P][G];
    #pragma unroll
    for (int p = 0; p < P; ++p)
        #pragma unroll
        for (int g = 0; g < G; ++g) acc[p][g] = 0u;

    uint4 pt[P];
    #pragma unroll
    for (int p = 0; p < P; ++p) pt[p] = rp[p * 8];

    for (int c = 0; c < 8; ++c) {
        uint4 nx[P];
        if (c < 7) {
            #pragma unroll
            for (int p = 0; p < P; ++p) nx[p] = rp[p * 8 + c + 1];
        } else {
            #pragma unroll
            for (int p = 0; p < P; ++p) nx[p] = pt[p];
        }
        #pragma unroll
        for (int g = 0; g < G; ++g) {
            const uint4 s = sa[g][c];
            #pragma unroll
            for (int p = 0; p < P; ++p) {
                unsigned a = acc[p][g];
                a = sad8(pt[p].x, s.x, a);
                a = sad8(pt[p].y, s.y, a);
                a = sad8(pt[p].z, s.z, a);
                a = sad8(pt[p].w, s.w, a);
                acc[p][g] = a;
            }
        }
        #pragma unroll
        for (int p = 0; p < P; ++p) pt[p] = nx[p];
    }

    if (valid) {
        #pragma unroll
        for (int g = 0; g < G; ++g) {
            uint2 w;
            w.x = acc[0][g] | (acc[1][g] << 16);
            w.y = acc[2][g] | (acc[3][g] << 16);
            *(uint2*)(wsd + (size_t)(t0 - chunk_start + g) * NPTS + n0) = w;
        }
    }

    // fused per-task min (register/shuffle only)
    const int lane = tid & 63, wv = tid >> 6;
    #pragma unroll
    for (int g = 0; g < G; ++g) {
        unsigned m0 = min(min(acc[0][g], acc[1][g]), min(acc[2][g], acc[3][g]));
        unsigned m = valid ? m0 : 0xFFFFFFFFu;
        #pragma unroll
        for (int off = 32; off >= 1; off >>= 1) {
            const unsigned o = (unsigned)__shfl_xor((int)m, off);
            m = m < o ? m : o;
        }
        if (lane == 0) smin[wv][g] = m;
    }
    __syncthreads();
    if (tid < G) {
        unsigned m = smin[0][tid];
        m = m < smin[1][tid] ? m : smin[1][tid];
        m = m < smin[2][tid] ? m : smin[2][tid];
        m = m < smin[3][tid] ? m : smin[3][tid];
        atomicMin(&gmin[t0 + tid], m);
    }
}

// One block per task, SINGLE streaming pass: points with d - min < WIN
// (~4% of row for concentrated L1 distances) enter an LDS candidate list +
// 64-bin fine histogram; exact kth from the tiny list; relu-sum over list.
// Exact full-row radix fallback if the window misses K or the list overflows.
__global__ __launch_bounds__(256) void select_kernel(
    const float* __restrict__ o1, const float* __restrict__ o2,
    const int* __restrict__ anchor1, const int* __restrict__ anchor2,
    const u16t* __restrict__ wsd, const unsigned* __restrict__ gmin,
    const unsigned* __restrict__ gmax, int chunk_start, float* __restrict__ d_out)
{
    __shared__ float red[256];
    __shared__ unsigned h64[NB];
    __shared__ unsigned h16[16];
    __shared__ unsigned h256[256];
    __shared__ u16t lst[CAP];
    __shared__ unsigned s_cnt, s_kbin, s_rem, s_kth, s_remf, s_fb;

    const int tid = threadIdx.x;
    const int t = chunk_start + (int)blockIdx.x;
    const u16t* R = wsd + (size_t)blockIdx.x * NPTS;

    // D = pos + GAMMA (exact fp32 from originals)
    const int a = (t < NA) ? t : (t - NA);
    const int i1 = anchor1[a], i2 = anchor2[a];
    float p = 0.0f;
    if (tid < DIM) p = fabsf(o1[(size_t)i1 * DIM + tid] - o2[(size_t)i2 * DIM + tid]);
    red[tid] = p;
    __syncthreads();
    for (int s = 128; s >= 1; s >>= 1) { if (tid < s) red[tid] += red[tid + s]; __syncthreads(); }
    const float D = red[0] + GAMMA;
    __syncthreads();

    const float M = __uint_as_float(*gmax);
    const float dq = 2.0f * M / 255.0f;     // u8-metric count -> float distance
    const unsigned mn = gmin[t];

    if (tid < NB) h64[tid] = 0u;
    if (tid < 16) h16[tid] = 0u;
    if (tid == 0) { s_cnt = 0u; s_fb = 0u; }
    __syncthreads();

    // ---- single pass: window filter -> candidates + fine histogram ----
    const uint4* R4 = (const uint4*)R;      // 2500 uint4 (8 u16 each)
    for (int i = tid; i < NPTS / 8; i += 256) {
        const uint4 v = R4[i];
        const unsigned w[4] = {v.x, v.y, v.z, v.w};
        #pragma unroll
        for (int j = 0; j < 4; ++j) {
            #pragma unroll
            for (int h = 0; h < 2; ++h) {
                const unsigned u = h ? (w[j] >> 16) : (w[j] & 0xFFFFu);
                const unsigned rel = u - mn;          // u >= mn always
                if (rel < WIN) {
                    const unsigned ix = atomicAdd(&s_cnt, 1u);
                    if (ix < CAP) lst[ix] = (u16t)u;
                    atomicAdd(&h64[rel >> 4], 1u);
                }
            }
        }
    }
    __syncthreads();
    const unsigned cnt = s_cnt;

    // kth fine bin (serial over 64 entries, trivial)
    if (tid == 0) {
        unsigned cum = 0, b;
        s_fb = 1u;
        for (b = 0; b < NB; ++b) {
            const unsigned c = h64[b];
            if (cum + c >= KSEL) { s_kbin = b; s_rem = KSEL - cum; s_fb = 0u; break; }
            cum += c;
        }
    }
    __syncthreads();

    float local = 0.0f;
    unsigned kth, remf;

    if (!s_fb && cnt <= CAP) {
        const unsigned kbin = s_kbin;
        const unsigned rem0 = s_rem;
        // exact kth within the 16-wide fine bin via low-nibble count
        for (int i = tid; i < (int)cnt; i += 256) {
            const unsigned rel = (unsigned)lst[i] - mn;
            if ((rel >> 4) == kbin) atomicAdd(&h16[rel & 15u], 1u);
        }
        __syncthreads();
        if (tid == 0) {
            unsigned rem = rem0, b = 0;
            for (;; ++b) { const unsigned c = h16[b]; if (c >= rem) break; rem -= c; }
            s_kth = mn + (kbin << 4) + b; s_remf = rem;
        }
        __syncthreads();
        kth = s_kth; remf = s_remf;
        for (int i = tid; i < (int)cnt; i += 256) {
            const unsigned k = lst[i];
            if (k < kth) local += fmaxf(D - (float)k * dq, 0.0f);
        }
    } else {
        // exact fallback: 2-level radix over the full row
        h256[tid] = 0u;
        __syncthreads();
        for (int i = tid; i < NPTS; i += 256) atomicAdd(&h256[R[i] >> 8], 1u);
        __syncthreads();
        if (tid == 0) {
            unsigned rem = KSEL, b = 0;
            for (;; ++b) { const unsigned c = h256[b]; if (c >= rem) break; rem -= c; }
            s_kbin = b; s_rem = rem;
        }
        __syncthreads();
        const unsigned b0 = s_kbin;
        const unsigned r1 = s_rem;
        __syncthreads();
        h256[tid] = 0u;
        __syncthreads();
        for (int i = tid; i < NPTS; i += 256)
            if ((unsigned)(R[i] >> 8) == b0) atomicAdd(&h256[R[i] & 0xFFu], 1u);
        __syncthreads();
        if (tid == 0) {
            unsigned rem = r1, b = 0;
            for (;; ++b) { const unsigned c = h256[b]; if (c >= rem) break; rem -= c; }
            s_kth = (b0 << 8) | b; s_remf = rem;
        }
        __syncthreads();
        kth = s_kth; remf = s_remf;
        for (int i = tid; i < NPTS; i += 256) {
            const unsigned u = R[i];
            if (u < kth) local += fmaxf(D - (float)u * dq, 0.0f);
        }
    }

    red[tid] = local;
    __syncthreads();
    for (int s = 128; s >= 1; s >>= 1) { if (tid < s) red[tid] += red[tid + s]; __syncthreads(); }
    if (tid == 0) {
        const float total = red[0] + (float)remf * fmaxf(D - (float)kth * dq, 0.0f);
        atomicAdd(d_out, total * (1.0f / ((float)NA * (float)KSEL)));
    }
}

extern "C" void kernel_launch(void* const* d_in, const int* in_sizes, int n_in,
                              void* d_out, int out_size, void* d_ws, size_t ws_size,
                              hipStream_t stream) {
    const float* o1 = (const float*)d_in[0];
    const float* o2 = (const float*)d_in[1];
    const int*   a1 = (const int*)d_in[2];
    const int*   a2 = (const int*)d_in[3];
    float* out = (float*)d_out;

    // ws layout from 16B-aligned end: [gmax 16B][gmin 8KB][q2 2.56MB][q1 2.56MB];
    // u16 distance rows from the base.
    const size_t qbytes = (size_t)NPTS * DIM;            // u8 rows
    const uintptr_t end = ((uintptr_t)d_ws + ws_size) & ~(uintptr_t)15;
    unsigned* gmax = (unsigned*)(end - 16);
    unsigned* gmin = (unsigned*)(end - 16 - (size_t)NTASK * 4);
    u8t*      q2   = (u8t*)((uintptr_t)gmin - qbytes);
    u8t*      q1   = (u8t*)((uintptr_t)q2 - qbytes);
    u16t*     wsd  = (u16t*)d_ws;

    const size_t dist_region = (uintptr_t)q1 - (uintptr_t)d_ws;
    int chunk = (int)(dist_region / ((size_t)NPTS * 2));
    chunk -= chunk % G;
    if (chunk < G) chunk = G;
    if (chunk > NTASK) chunk = NTASK;

    init_kernel<<<(NTASK + 255) / 256, 256, 0, stream>>>(out, gmin, gmax);
    maxabs_kernel<<<1024, 256, 0, stream>>>(o1, o2, gmax);
    quant_kernel<<<1280, 256, 0, stream>>>(o1, o2, q1, q2, gmax);

    for (int start = 0; start < NTASK; start += chunk) {
        int cur = NTASK - start;
        if (cur > chunk) cur = chunk;
        dim3 gd(cur / G, (NPTS + TILE - 1) / TILE);
        dist_kernel<<<gd, 256, 0, stream>>>(q1, q2, a1, a2, wsd, gmin, start);
        select_kernel<<<cur, 256, 0, stream>>>(o1, o2, a1, a2, wsd, gmin, gmax, start, out);
    }
}

// Round 6
// 223.002 us; speedup vs baseline: 1.6819x; 1.6819x over previous
//
#include <hip/hip_runtime.h>
#include <hip/hip_bf16.h>

#define NPTS  20000
#define DIM   128
#define NA    1024
#define NTASK 2048
#define G     8        // tasks per dist block
#define P     4        // points per thread (wave-strided)
#define TILE  1024     // points per dist block (4 waves * 64 lanes * P)
#define KSEL  50
#define GAMMA 1.0f
#define WIN   512      // candidate window above per-task min (u8-metric units)
#define NB    32       // fine bins in window (width 16)
#define CAP   4096

typedef unsigned char  u8t;
typedef unsigned short u16t;

static __device__ __forceinline__ unsigned sad8(unsigned a, unsigned b, unsigned c) {
#if __has_builtin(__builtin_amdgcn_sad_u8)
    return __builtin_amdgcn_sad_u8(a, b, c);
#else
    unsigned d;
    asm("v_sad_u8 %0, %1, %2, %3" : "=v"(d) : "v"(a), "v"(b), "v"(c));
    return d;
#endif
}

__global__ __launch_bounds__(256) void init_kernel(float* out, unsigned* gmin, unsigned* gmax) {
    const int i = (int)blockIdx.x * 256 + (int)threadIdx.x;
    if (i < NTASK) gmin[i] = 0xFFFFFFFFu;
    if (i == 0) { out[0] = 0.0f; gmax[0] = 0u; }
}

__global__ __launch_bounds__(256) void maxabs_kernel(
    const float* __restrict__ o1, const float* __restrict__ o2,
    unsigned* __restrict__ gmax)
{
    const int nt = (int)gridDim.x * 256;
    const float4* a = (const float4*)o1;
    const float4* b = (const float4*)o2;
    float m = 0.0f;
    for (int i = (int)blockIdx.x * 256 + (int)threadIdx.x; i < NPTS * DIM / 4; i += nt) {
        const float4 x = a[i], y = b[i];
        m = fmaxf(m, fmaxf(fmaxf(fabsf(x.x), fabsf(x.y)), fmaxf(fabsf(x.z), fabsf(x.w))));
        m = fmaxf(m, fmaxf(fmaxf(fabsf(y.x), fabsf(y.y)), fmaxf(fabsf(y.z), fabsf(y.w))));
    }
    #pragma unroll
    for (int off = 32; off >= 1; off >>= 1) m = fmaxf(m, __shfl_xor(m, off));
    if ((threadIdx.x & 63) == 0) atomicMax(gmax, __float_as_uint(m));  // m >= 0: bit order == float order
}

static __device__ __forceinline__ unsigned q4(const float4 v, const float M, const float s) {
    unsigned u0 = __float2uint_rn((v.x + M) * s); if (u0 > 255u) u0 = 255u;
    unsigned u1 = __float2uint_rn((v.y + M) * s); if (u1 > 255u) u1 = 255u;
    unsigned u2 = __float2uint_rn((v.z + M) * s); if (u2 > 255u) u2 = 255u;
    unsigned u3 = __float2uint_rn((v.w + M) * s); if (u3 > 255u) u3 = 255u;
    return u0 | (u1 << 8) | (u2 << 16) | (u3 << 24);
}

// Writes transpose-packed layout: qp[m][cq*NPTS + n] = uint4 holding dims
// 16*cq..16*cq+15 of point n (so lanes with consecutive n load coalesced).
__global__ __launch_bounds__(256) void quant_pack_kernel(
    const float* __restrict__ o1, const float* __restrict__ o2,
    uint4* __restrict__ qp1, uint4* __restrict__ qp2,
    const unsigned* __restrict__ gmax)
{
    const float M = __uint_as_float(*gmax);
    const float s = 255.0f / (2.0f * M);
    const int nt = (int)gridDim.x * 256;
    for (int idx = (int)blockIdx.x * 256 + (int)threadIdx.x; idx < 2 * 8 * NPTS; idx += nt) {
        const int m  = idx / (8 * NPTS);
        const int r  = idx - m * (8 * NPTS);
        const int cq = r / NPTS;
        const int n  = r - cq * NPTS;
        const float4* src = (const float4*)((m ? o2 : o1) + (size_t)n * DIM + cq * 16);
        uint4 o;
        o.x = q4(src[0], M, s);
        o.y = q4(src[1], M, s);
        o.z = q4(src[2], M, s);
        o.w = q4(src[3], M, s);
        (m ? qp2 : qp1)[(size_t)cq * NPTS + n] = o;
    }
}

// Gather + quantize anchor rows: astage[cq*NTASK + t] (same quantization).
__global__ __launch_bounds__(256) void astage_kernel(
    const float* __restrict__ o1, const float* __restrict__ o2,
    const int* __restrict__ anchor1, const int* __restrict__ anchor2,
    uint4* __restrict__ astage, const unsigned* __restrict__ gmax)
{
    const float M = __uint_as_float(*gmax);
    const float s = 255.0f / (2.0f * M);
    const int idx = (int)blockIdx.x * 256 + (int)threadIdx.x;
    if (idx >= NTASK * 8) return;
    const int t = idx >> 3, cq = idx & 7;
    int row; const float* src;
    if (t < NA) { row = anchor1[t];      src = o1; }
    else        { row = anchor2[t - NA]; src = o2; }
    const float4* rp = (const float4*)(src + (size_t)row * DIM + cq * 16);
    uint4 o;
    o.x = q4(rp[0], M, s);
    o.y = q4(rp[1], M, s);
    o.z = q4(rp[2], M, s);
    o.w = q4(rp[3], M, s);
    astage[(size_t)cq * NTASK + t] = o;
}

// L1 distances via v_sad_u8. Anchors come from astage via block-uniform
// addresses -> scalar loads -> SGPR operand of v_sad_u8 (no LDS at all).
// Point loads are coalesced (transpose-packed planes, lane-consecutive n).
__global__ __launch_bounds__(256) void dist_kernel(
    const uint4* __restrict__ qp1, const uint4* __restrict__ qp2,
    const uint4* __restrict__ astage,
    u16t* __restrict__ wsd, unsigned* __restrict__ gmin, int chunk_start)
{
    __shared__ unsigned smin[4][G];

    const int tid = threadIdx.x;
    const int t0 = chunk_start + (int)blockIdx.x * G;
    const uint4* qp = (t0 < NA) ? qp2 : qp1;

    const int w = tid >> 6, l = tid & 63;
    const int nbase = (int)blockIdx.y * TILE + w * 256 + l;   // point p: nbase + p*64

    unsigned acc[P][G];
    #pragma unroll
    for (int p = 0; p < P; ++p)
        #pragma unroll
        for (int g = 0; g < G; ++g) acc[p][g] = 0u;

    #pragma unroll
    for (int cq = 0; cq < 8; ++cq) {
        uint4 A[G];
        #pragma unroll
        for (int g = 0; g < G; ++g) A[g] = astage[(size_t)cq * NTASK + t0 + g];  // uniform -> s_load
        uint4 pv[P];
        #pragma unroll
        for (int p = 0; p < P; ++p) {
            int n = nbase + p * 64;
            n = n < NPTS ? n : NPTS - 1;   // clamped load, store predicated below
            pv[p] = qp[(size_t)cq * NPTS + n];
        }
        #pragma unroll
        for (int g = 0; g < G; ++g) {
            #pragma unroll
            for (int p = 0; p < P; ++p) {
                unsigned a = acc[p][g];
                a = sad8(pv[p].x, A[g].x, a);
                a = sad8(pv[p].y, A[g].y, a);
                a = sad8(pv[p].z, A[g].z, a);
                a = sad8(pv[p].w, A[g].w, a);
                acc[p][g] = a;
            }
        }
    }

    #pragma unroll
    for (int p = 0; p < P; ++p) {
        const int n = nbase + p * 64;
        if (n < NPTS) {
            #pragma unroll
            for (int g = 0; g < G; ++g)
                wsd[(size_t)(t0 - chunk_start + g) * NPTS + n] = (u16t)acc[p][g];
        }
    }

    // fused per-task min (register/shuffle only, 1 atomicMin per task per block)
    #pragma unroll
    for (int g = 0; g < G; ++g) {
        unsigned m = 0xFFFFFFFFu;
        #pragma unroll
        for (int p = 0; p < P; ++p) {
            const unsigned v = (nbase + p * 64 < NPTS) ? acc[p][g] : 0xFFFFFFFFu;
            m = m < v ? m : v;
        }
        #pragma unroll
        for (int off = 32; off >= 1; off >>= 1) {
            const unsigned o = (unsigned)__shfl_xor((int)m, off);
            m = m < o ? m : o;
        }
        if (l == 0) smin[w][g] = m;
    }
    __syncthreads();
    if (tid < G) {
        unsigned m = smin[0][tid];
        m = m < smin[1][tid] ? m : smin[1][tid];
        m = m < smin[2][tid] ? m : smin[2][tid];
        m = m < smin[3][tid] ? m : smin[3][tid];
        atomicMin(&gmin[t0 + tid], m);
    }
}

// One block per task, single streaming pass: points with d - min < WIN(=2.2
// sigma) enter an LDS candidate list (~900 expected) + 32-bin fine histogram;
// exact kth from the list; relu-sum over list. Exact full-row radix fallback.
__global__ __launch_bounds__(256) void select_kernel(
    const float* __restrict__ o1, const float* __restrict__ o2,
    const int* __restrict__ anchor1, const int* __restrict__ anchor2,
    const u16t* __restrict__ wsd, const unsigned* __restrict__ gmin,
    const unsigned* __restrict__ gmax, int chunk_start, float* __restrict__ d_out)
{
    __shared__ float red[256];
    __shared__ unsigned h32[NB];
    __shared__ unsigned h16[16];
    __shared__ unsigned h256[256];
    __shared__ u16t lst[CAP];
    __shared__ unsigned s_cnt, s_kbin, s_rem, s_kth, s_remf, s_fb;

    const int tid = threadIdx.x;
    const int t = chunk_start + (int)blockIdx.x;
    const u16t* R = wsd + (size_t)blockIdx.x * NPTS;

    // D = pos + GAMMA (exact fp32 from originals)
    const int a = (t < NA) ? t : (t - NA);
    const int i1 = anchor1[a], i2 = anchor2[a];
    float p = 0.0f;
    if (tid < DIM) p = fabsf(o1[(size_t)i1 * DIM + tid] - o2[(size_t)i2 * DIM + tid]);
    red[tid] = p;
    __syncthreads();
    for (int s = 128; s >= 1; s >>= 1) { if (tid < s) red[tid] += red[tid + s]; __syncthreads(); }
    const float D = red[0] + GAMMA;
    __syncthreads();

    const float M = __uint_as_float(*gmax);
    const float dq = 2.0f * M / 255.0f;     // u8-metric count -> float distance
    const unsigned mn = gmin[t];

    if (tid < NB) h32[tid] = 0u;
    if (tid < 16) h16[tid] = 0u;
    if (tid == 0) { s_cnt = 0u; s_fb = 0u; }
    __syncthreads();

    // ---- single pass: window filter -> candidates + fine histogram ----
    const uint4* R4 = (const uint4*)R;      // 2500 uint4 (8 u16 each)
    for (int i = tid; i < NPTS / 8; i += 256) {
        const uint4 v = R4[i];
        const unsigned wv[4] = {v.x, v.y, v.z, v.w};
        #pragma unroll
        for (int j = 0; j < 4; ++j) {
            #pragma unroll
            for (int h = 0; h < 2; ++h) {
                const unsigned u = h ? (wv[j] >> 16) : (wv[j] & 0xFFFFu);
                const unsigned rel = u - mn;          // u >= mn always
                if (rel < WIN) {
                    const unsigned ix = atomicAdd(&s_cnt, 1u);
                    if (ix < CAP) lst[ix] = (u16t)u;
                    atomicAdd(&h32[rel >> 4], 1u);
                }
            }
        }
    }
    __syncthreads();
    const unsigned cnt = s_cnt;

    // kth fine bin (serial over 32 entries)
    if (tid == 0) {
        unsigned cum = 0, b;
        s_fb = 1u;
        for (b = 0; b < NB; ++b) {
            const unsigned c = h32[b];
            if (cum + c >= KSEL) { s_kbin = b; s_rem = KSEL - cum; s_fb = 0u; break; }
            cum += c;
        }
    }
    __syncthreads();

    float local = 0.0f;
    unsigned kth, remf;

    if (!s_fb && cnt <= CAP) {
        const unsigned kbin = s_kbin;
        const unsigned rem0 = s_rem;
        for (int i = tid; i < (int)cnt; i += 256) {
            const unsigned rel = (unsigned)lst[i] - mn;
            if ((rel >> 4) == kbin) atomicAdd(&h16[rel & 15u], 1u);
        }
        __syncthreads();
        if (tid == 0) {
            unsigned rem = rem0, b = 0;
            for (;; ++b) { const unsigned c = h16[b]; if (c >= rem) break; rem -= c; }
            s_kth = mn + (kbin << 4) + b; s_remf = rem;
        }
        __syncthreads();
        kth = s_kth; remf = s_remf;
        for (int i = tid; i < (int)cnt; i += 256) {
            const unsigned k = lst[i];
            if (k < kth) local += fmaxf(D - (float)k * dq, 0.0f);
        }
    } else {
        // exact fallback: 2-level radix over the full row
        h256[tid] = 0u;
        __syncthreads();
        for (int i = tid; i < NPTS; i += 256) atomicAdd(&h256[R[i] >> 8], 1u);
        __syncthreads();
        if (tid == 0) {
            unsigned rem = KSEL, b = 0;
            for (;; ++b) { const unsigned c = h256[b]; if (c >= rem) break; rem -= c; }
            s_kbin = b; s_rem = rem;
        }
        __syncthreads();
        const unsigned b0 = s_kbin;
        const unsigned r1 = s_rem;
        __syncthreads();
        h256[tid] = 0u;
        __syncthreads();
        for (int i = tid; i < NPTS; i += 256)
            if ((unsigned)(R[i] >> 8) == b0) atomicAdd(&h256[R[i] & 0xFFu], 1u);
        __syncthreads();
        if (tid == 0) {
            unsigned rem = r1, b = 0;
            for (;; ++b) { const unsigned c = h256[b]; if (c >= rem) break; rem -= c; }
            s_kth = (b0 << 8) | b; s_remf = rem;
        }
        __syncthreads();
        kth = s_kth; remf = s_remf;
        for (int i = tid; i < NPTS; i += 256) {
            const unsigned u = R[i];
            if (u < kth) local += fmaxf(D - (float)u * dq, 0.0f);
        }
    }

    red[tid] = local;
    __syncthreads();
    for (int s = 128; s >= 1; s >>= 1) { if (tid < s) red[tid] += red[tid + s]; __syncthreads(); }
    if (tid == 0) {
        const float total = red[0] + (float)remf * fmaxf(D - (float)kth * dq, 0.0f);
        atomicAdd(d_out, total * (1.0f / ((float)NA * (float)KSEL)));
    }
}

extern "C" void kernel_launch(void* const* d_in, const int* in_sizes, int n_in,
                              void* d_out, int out_size, void* d_ws, size_t ws_size,
                              hipStream_t stream) {
    const float* o1 = (const float*)d_in[0];
    const float* o2 = (const float*)d_in[1];
    const int*   a1 = (const int*)d_in[2];
    const int*   a2 = (const int*)d_in[3];
    float* out = (float*)d_out;

    // ws layout from 16B-aligned end:
    // [gmax 16B][gmin 8KB][astage 256KB][qp2 2.56MB][qp1 2.56MB]; u16 rows at base.
    const size_t qbytes = (size_t)NPTS * DIM;            // one packed matrix
    const size_t abytes = (size_t)NTASK * DIM;           // anchor staging
    const uintptr_t end = ((uintptr_t)d_ws + ws_size) & ~(uintptr_t)15;
    unsigned* gmax   = (unsigned*)(end - 16);
    unsigned* gmin   = (unsigned*)(end - 16 - (size_t)NTASK * 4);
    uint4*    astage = (uint4*)((uintptr_t)gmin - abytes);
    uint4*    qp2    = (uint4*)((uintptr_t)astage - qbytes);
    uint4*    qp1    = (uint4*)((uintptr_t)qp2 - qbytes);
    u16t*     wsd    = (u16t*)d_ws;

    const size_t dist_region = (uintptr_t)qp1 - (uintptr_t)d_ws;
    int chunk = (int)(dist_region / ((size_t)NPTS * 2));
    chunk -= chunk % G;
    if (chunk < G) chunk = G;
    if (chunk > NTASK) chunk = NTASK;

    init_kernel<<<(NTASK + 255) / 256, 256, 0, stream>>>(out, gmin, gmax);
    maxabs_kernel<<<1024, 256, 0, stream>>>(o1, o2, gmax);
    quant_pack_kernel<<<1250, 256, 0, stream>>>(o1, o2, qp1, qp2, gmax);
    astage_kernel<<<(NTASK * 8 + 255) / 256, 256, 0, stream>>>(o1, o2, a1, a2, astage, gmax);

    for (int start = 0; start < NTASK; start += chunk) {
        int cur = NTASK - start;
        if (cur > chunk) cur = chunk;
        dim3 gd(cur / G, (NPTS + TILE - 1) / TILE);
        dist_kernel<<<gd, 256, 0, stream>>>(qp1, qp2, astage, wsd, gmin, start);
        select_kernel<<<cur, 256, 0, stream>>>(o1, o2, a1, a2, wsd, gmin, gmax, start, out);
    }
}